// Round 1
// baseline (510.275 us; speedup 1.0000x reference)
//
#include <hip/hip_runtime.h>

// y = x @ (weight * blockscale)^T ; x[8192,4096] f32, weight[4096,4096] f32,
// w_scale[32,32] f32, out f32 [8192,4096].
#define M_DIM 8192
#define K_DIM 4096
#define O_DIM 4096
#define QB    128
#define BK    64     // K per tile
#define BMT   256    // 256x256 output tile, 8 waves (2M x 4N)
#define BNT   256

typedef __attribute__((ext_vector_type(8))) short  short8;   // 8 bf16
typedef __attribute__((ext_vector_type(4))) float  floatx4;  // MFMA acc

#define AS1 __attribute__((address_space(1)))
#define AS3 __attribute__((address_space(3)))

// fp32 -> bf16 bits, round-to-nearest-even
__device__ __forceinline__ short f2bf(float f) {
    unsigned u = __float_as_uint(f);
    unsigned r = u + 0x7fffu + ((u >> 16) & 1u);
    return (short)(r >> 16);
}

// ---- fused pre-pass: x -> bf16, weight*scale -> bf16, one dispatch ----
// Plain (cached) loads: NT hints suspected of capping this kernel ~1.3 TB/s;
// the 6.3 TB/s measured ceiling is the plain-float4 path.
__global__ __launch_bounds__(512) void cvt_fused(const float* __restrict__ x,
                                                 const float* __restrict__ w,
                                                 const float* __restrict__ s,
                                                 short* __restrict__ xb,
                                                 short* __restrict__ wb) {
    const size_t NX = (size_t)M_DIM * K_DIM / 8;   // x threads
    size_t t = (size_t)blockIdx.x * 512 + threadIdx.x;
    if (t < NX) {
        size_t i = t * 8;
        floatx4 f0 = *(const floatx4*)(x + i);
        floatx4 f1 = *(const floatx4*)(x + i + 4);
        short8 o;
        o[0] = f2bf(f0[0]); o[1] = f2bf(f0[1]); o[2] = f2bf(f0[2]); o[3] = f2bf(f0[3]);
        o[4] = f2bf(f1[0]); o[5] = f2bf(f1[1]); o[6] = f2bf(f1[2]); o[7] = f2bf(f1[3]);
        *(short8*)(xb + i) = o;
    } else {
        size_t i = (t - NX) * 8;
        int o = (int)(i >> 12);            // / K_DIM
        int k = (int)(i & (K_DIM - 1));
        float sc = s[(o >> 7) * (K_DIM / QB) + (k >> 7)];
        floatx4 f0 = *(const floatx4*)(w + i);
        floatx4 f1 = *(const floatx4*)(w + i + 4);
        short8 v;
        v[0] = f2bf(f0[0] * sc); v[1] = f2bf(f0[1] * sc);
        v[2] = f2bf(f0[2] * sc); v[3] = f2bf(f0[3] * sc);
        v[4] = f2bf(f1[0] * sc); v[5] = f2bf(f1[1] * sc);
        v[6] = f2bf(f1[2] * sc); v[7] = f2bf(f1[3] * sc);
        *(short8*)(wb + i) = v;
    }
}

// ---- 256x256 8-phase bf16 GEMM (T1+T2+T3+T4+T5) ----
// 8 waves: wr = wave>>2 (2 along M, 128 rows each), wc = wave&3 (4 along N,
// 64 cols each). Per wave acc = 8x4 fragments of 16x16 (128 VGPR).
// LDS 128 KiB: lsA/lsB[2 bufs][256 rows][64 shorts]; tile t -> buf t&1.
// Rows are 64 shorts = 8 chunks of 16B; physical chunk = logical ^ (row&7)
// (2-way bank aliasing = free, m136). global_load_lds dest is lane-linear
// (tid*16B); the inverse swizzle rides on the global k-offset (same-row 128B
// segment -> still coalesced).
//
// Phase schedule per iteration (tiles T0=2i in buf0, T1=2i+1 in buf1):
//  p0: read a0,b0(T0)     | stage B(T1) h0   p4: read a0,b0(T1) | stage B(T2) h0
//  p1: read a1,b1(T0)     | stage B(T1) h1   p5: read a1,b1(T1) | stage B(T2) h1
//  p2:                    | stage A(T2) h0   p6:                | stage A(T3) h0
//  p3: vmcnt(4)           | stage A(T2) h1   p7: vmcnt(4)       | stage A(T3) h1
// All reads of a buffer happen in the first 2 of its 4 phases, so stages into
// it (2 phases later) never race. vmcnt(4) leaves 2 half-tiles (4 loads) in
// flight across the barrier -- the counted-vmcnt pipeline (T4).
#define WAIT_LGKM asm volatile("s_waitcnt lgkmcnt(0)" ::: "memory")
#define WAIT_VM4  asm volatile("s_waitcnt vmcnt(4)" ::: "memory")
#define WAIT_VM0  asm volatile("s_waitcnt vmcnt(0)" ::: "memory")
#define BARR      __builtin_amdgcn_s_barrier()
#define SCHEDB    __builtin_amdgcn_sched_barrier(0)

#define LDA4(DST, BUF, ROFF)                                                    \
    _Pragma("unroll")                                                           \
    for (int mi = 0; mi < 4; ++mi) {                                            \
        DST[mi][0] = *(const short8*)&lsA[BUF][rA + (ROFF) + mi * 1024 + pc0];  \
        DST[mi][1] = *(const short8*)&lsA[BUF][rA + (ROFF) + mi * 1024 + pc1];  \
    }

#define LDB2(DST, BUF, ROFF)                                                    \
    _Pragma("unroll")                                                           \
    for (int ni = 0; ni < 2; ++ni) {                                            \
        DST[ni][0] = *(const short8*)&lsB[BUF][rB + (ROFF) + ni * 1024 + pc0];  \
        DST[ni][1] = *(const short8*)&lsB[BUF][rB + (ROFF) + ni * 1024 + pc1];  \
    }

#define MM16(AF, BF, MO, NO)                                                    \
    _Pragma("unroll")                                                           \
    for (int mi = 0; mi < 4; ++mi)                                              \
        _Pragma("unroll")                                                       \
        for (int ni = 0; ni < 2; ++ni)                                          \
            _Pragma("unroll")                                                   \
            for (int ks = 0; ks < 2; ++ks)                                      \
                acc[(MO) + mi][(NO) + ni] = __builtin_amdgcn_mfma_f32_16x16x32_bf16( \
                    AF[mi][ks], BF[ni][ks], acc[(MO) + mi][(NO) + ni], 0, 0, 0);

#define STAGE(LS, BUF, GP, KOFF, H)                                             \
    __builtin_amdgcn_global_load_lds(                                           \
        (const AS1 void*)((GP) + (size_t)((H) * 128) * K_DIM + (KOFF)),         \
        (AS3 void*)&LS[BUF][(H) * 128 * BK + dst], 16, 0, 0);                   \
    __builtin_amdgcn_global_load_lds(                                           \
        (const AS1 void*)((GP) + (size_t)((H) * 128 + 64) * K_DIM + (KOFF)),    \
        (AS3 void*)&LS[BUF][((H) * 128 + 64) * BK + dst], 16, 0, 0);

#define MFMA_PH(...)                                                            \
    BARR;                                                                       \
    WAIT_LGKM;                                                                  \
    SCHEDB;                                                                     \
    __builtin_amdgcn_s_setprio(1);                                              \
    __VA_ARGS__                                                                 \
    __builtin_amdgcn_s_setprio(0);                                              \
    BARR;                                                                       \
    SCHEDB;

__global__ __launch_bounds__(512, 2) void gemm_bt(const short* __restrict__ A,
                                                  const short* __restrict__ B,
                                                  float* __restrict__ C) {
    __shared__ __align__(16) short lsA[2][BMT * BK];   // 64 KiB
    __shared__ __align__(16) short lsB[2][BNT * BK];   // 64 KiB

    const int tid  = threadIdx.x;
    const int lane = tid & 63;
    const int wave = tid >> 6;
    const int wr   = wave >> 2;     // 0..1
    const int wc   = wave & 3;      // 0..3

    // bijective XCD map: 512 blocks, 64 per XCD; XCD x owns bn stripe
    // {2x, 2x+1} (2x256 cols x 4096 k x 2B = 4 MiB of B in its L2);
    // consecutive j alternate bn within one bm -> A tile (2 MiB) reused hot.
    const int id  = blockIdx.x;
    const int xcd = id & 7;
    const int j   = id >> 3;
    const int bm  = j >> 1;                  // 0..31
    const int bn  = (xcd << 1) | (j & 1);    // 0..15

    // staging: thread covers row sr=tid>>3 (+64 per second load), phys chunk
    // tid&7; logical chunk = (tid&7)^(sr&7), invariant under row+64/+128.
    const int sr  = tid >> 3;
    const int csw = ((tid & 7) ^ (sr & 7)) << 3;
    const int dst = tid * 8;                 // = sr*64 + (tid&7)*8
    const short* gA = A + (size_t)(bm * BMT + sr) * K_DIM + csw;
    const short* gB = B + (size_t)(bn * BNT + sr) * K_DIM + csw;

    // fragment reads
    const int frow = lane & 15;
    const int fc   = lane >> 4;
    const int fsw  = frow & 7;
    const int pc0  = (fc ^ fsw) << 3;        // ks=0 physical chunk * 8
    const int pc1  = ((4 + fc) ^ fsw) << 3;  // ks=1
    const int rA   = (wr * 128 + frow) * BK;
    const int rB   = (wc * 64 + frow) * BK;

    floatx4 acc[8][4];
#pragma unroll
    for (int mi = 0; mi < 8; ++mi)
#pragma unroll
        for (int ni = 0; ni < 4; ++ni)
            acc[mi][ni] = (floatx4){0.f, 0.f, 0.f, 0.f};

    short8 a0[4][2], a1[4][2], b0[2][2], b1[2][2];

    // prologue: tile0 A+B -> buf0, tile1 A -> buf1; wait tile0 (8 oldest).
    STAGE(lsA, 0, gA, 0, 0)
    STAGE(lsA, 0, gA, 0, 1)
    STAGE(lsB, 0, gB, 0, 0)
    STAGE(lsB, 0, gB, 0, 1)
    STAGE(lsA, 1, gA, 64, 0)
    STAGE(lsA, 1, gA, 64, 1)
    WAIT_VM4;
    BARR;
    SCHEDB;

#pragma unroll 1
    for (int it = 0; it < 31; ++it) {
        // ---- tile 2i from buf0 ----
        LDA4(a0, 0, 0)
        LDB2(b0, 0, 0)
        STAGE(lsB, 1, gB, 64, 0)
        MFMA_PH(MM16(a0, b0, 0, 0))

        LDA4(a1, 0, 4096)
        LDB2(b1, 0, 2048)
        STAGE(lsB, 1, gB, 64, 1)
        MFMA_PH(MM16(a0, b1, 0, 2))

        STAGE(lsA, 0, gA, 128, 0)
        MFMA_PH(MM16(a1, b0, 4, 0))

        STAGE(lsA, 0, gA, 128, 1)
        WAIT_VM4;                      // tile 2i+1 (A+B) complete; 4 in flight
        MFMA_PH(MM16(a1, b1, 4, 2))

        // ---- tile 2i+1 from buf1 ----
        LDA4(a0, 1, 0)
        LDB2(b0, 1, 0)
        STAGE(lsB, 0, gB, 128, 0)
        MFMA_PH(MM16(a0, b0, 0, 0))

        LDA4(a1, 1, 4096)
        LDB2(b1, 1, 2048)
        STAGE(lsB, 0, gB, 128, 1)
        MFMA_PH(MM16(a0, b1, 0, 2))

        STAGE(lsA, 1, gA, 192, 0)
        MFMA_PH(MM16(a1, b0, 4, 0))

        STAGE(lsA, 1, gA, 192, 1)
        WAIT_VM4;                      // tile 2i+2 (A+B) complete; 4 in flight
        MFMA_PH(MM16(a1, b1, 4, 2))

        gA += 2 * BK;
        gB += 2 * BK;
    }

    // epilogue: tiles 62 (buf0) + 63 (buf1); only B(t63) still to stage.
    LDA4(a0, 0, 0)
    LDB2(b0, 0, 0)
    STAGE(lsB, 1, gB, 64, 0)
    MFMA_PH(MM16(a0, b0, 0, 0))

    LDA4(a1, 0, 4096)
    LDB2(b1, 0, 2048)
    STAGE(lsB, 1, gB, 64, 1)
    MFMA_PH(MM16(a0, b1, 0, 2))

    MFMA_PH(MM16(a1, b0, 4, 0))

    WAIT_VM0;
    MFMA_PH(MM16(a1, b1, 4, 2))

    LDA4(a0, 1, 0)
    LDB2(b0, 1, 0)
    MFMA_PH(MM16(a0, b0, 0, 0))

    LDA4(a1, 1, 4096)
    LDB2(b1, 1, 2048)
    MFMA_PH(MM16(a0, b1, 0, 2))

    MFMA_PH(MM16(a1, b0, 4, 0))

    MFMA_PH(MM16(a1, b1, 4, 2))

    // Epilogue. C/D layout: col = lane&15, row = (lane>>4)*4 + reg.
    const int quad  = lane >> 4;
    const int crow0 = bm * BMT + wr * 128 + quad * 4;
    const int ccol0 = bn * BNT + wc * 64 + frow;
#pragma unroll
    for (int mi = 0; mi < 8; ++mi)
#pragma unroll
        for (int ni = 0; ni < 4; ++ni) {
            float* cp = C + (size_t)(crow0 + mi * 16) * O_DIM + (ccol0 + ni * 16);
#pragma unroll
            for (int r = 0; r < 4; ++r)
                cp[(size_t)r * O_DIM] = acc[mi][ni][r];
        }
}

extern "C" void kernel_launch(void* const* d_in, const int* in_sizes, int n_in,
                              void* d_out, int out_size, void* d_ws, size_t ws_size,
                              hipStream_t stream) {
    const float* x  = (const float*)d_in[0];
    const float* w  = (const float*)d_in[1];
    const float* ws = (const float*)d_in[2];
    float* out = (float*)d_out;

    short* xb = (short*)d_ws;                       // 64 MiB bf16 x
    short* wb = xb + (size_t)M_DIM * K_DIM;         // 32 MiB bf16 dequant w

    const size_t total_t = ((size_t)M_DIM * K_DIM + (size_t)O_DIM * K_DIM) / 8;
    cvt_fused<<<(unsigned)(total_t / 512), 512, 0, stream>>>(x, w, ws, xb, wb);

    gemm_bt<<<(M_DIM / BMT) * (O_DIM / BNT), 512, 0, stream>>>(xb, wb, out);
}

// Round 2
// 491.656 us; speedup vs baseline: 1.0379x; 1.0379x over previous
//
#include <hip/hip_runtime.h>

// y = x @ (weight * blockscale)^T ; x[8192,4096] f32, weight[4096,4096] f32,
// w_scale[32,32] f32, out f32 [8192,4096].
#define M_DIM 8192
#define K_DIM 4096
#define O_DIM 4096
#define QB    128
#define BK    64     // K per tile
#define BMT   256    // 256x256 output tile, 8 waves (2M x 4N)
#define BNT   256

typedef __attribute__((ext_vector_type(8))) short  short8;   // 8 bf16
typedef __attribute__((ext_vector_type(4))) float  floatx4;  // MFMA acc

#define AS1 __attribute__((address_space(1)))
#define AS3 __attribute__((address_space(3)))

// fp32 -> bf16 bits, round-to-nearest-even
__device__ __forceinline__ short f2bf(float f) {
    unsigned u = __float_as_uint(f);
    unsigned r = u + 0x7fffu + ((u >> 16) & 1u);
    return (short)(r >> 16);
}

// ---- fused pre-pass: x -> bf16, weight*scale -> bf16, one dispatch ----
// (unchanged this round for clean attribution; counters still unseen)
__global__ __launch_bounds__(512) void cvt_fused(const float* __restrict__ x,
                                                 const float* __restrict__ w,
                                                 const float* __restrict__ s,
                                                 short* __restrict__ xb,
                                                 short* __restrict__ wb) {
    const size_t NX = (size_t)M_DIM * K_DIM / 8;   // x threads
    size_t t = (size_t)blockIdx.x * 512 + threadIdx.x;
    if (t < NX) {
        size_t i = t * 8;
        floatx4 f0 = *(const floatx4*)(x + i);
        floatx4 f1 = *(const floatx4*)(x + i + 4);
        short8 o;
        o[0] = f2bf(f0[0]); o[1] = f2bf(f0[1]); o[2] = f2bf(f0[2]); o[3] = f2bf(f0[3]);
        o[4] = f2bf(f1[0]); o[5] = f2bf(f1[1]); o[6] = f2bf(f1[2]); o[7] = f2bf(f1[3]);
        *(short8*)(xb + i) = o;
    } else {
        size_t i = (t - NX) * 8;
        int o = (int)(i >> 12);            // / K_DIM
        int k = (int)(i & (K_DIM - 1));
        float sc = s[(o >> 7) * (K_DIM / QB) + (k >> 7)];
        floatx4 f0 = *(const floatx4*)(w + i);
        floatx4 f1 = *(const floatx4*)(w + i + 4);
        short8 v;
        v[0] = f2bf(f0[0] * sc); v[1] = f2bf(f0[1] * sc);
        v[2] = f2bf(f0[2] * sc); v[3] = f2bf(f0[3] * sc);
        v[4] = f2bf(f1[0] * sc); v[5] = f2bf(f1[1] * sc);
        v[6] = f2bf(f1[2] * sc); v[7] = f2bf(f1[3] * sc);
        *(short8*)(wb + i) = v;
    }
}

// ---- 256x256 8-phase bf16 GEMM, one-phase-ahead ds_reads ----
// Per tile t (buf c), quadrants Q0=(a0,b0) Q1=(a0,b1) Q2=(a1,b0) Q3=(a1,b1):
//  p0: rd b1,a1 (c)      | stage A(t+1)h1 | barrier | lgkm(12) | Q0
//  p1:                   | stage B(t+1)h0 | barrier | lgkm(8)  | Q1
//  p2:                   | stage B(t+1)h1 | barrier | lgkm(0)  | Q2
//  p3: stage A(t+2)h0 | vmcnt(2) | barrier | rd a0,b0 (n) | lgkm(12) | Q3
// Every MFMA's ds_reads were issued >=1 phase earlier -> they drain under the
// previous MFMA cluster instead of serializing with this one (round-1's
// 12-reads-then-lgkm0 pattern cost ~380 LDS-pipe cycles per phase in series
// with MFMA; model matched the measured 43.5% MfmaUtil).
// Safety: all reads of buf c are forced complete by p2's lgkm(0) + closing
// barrier before any stage into c issues at p3 -> no gload_lds/ds_read race.
// vmcnt(2): A(t+2)h0 stays in flight; youngest-waited load (B(t+1)h1) issued
// 1 phase before use (B is L2-resident, 32x block reuse); A has 3-4 phases.
#define WLG12 asm volatile("s_waitcnt lgkmcnt(12)" ::: "memory")
#define WLG8  asm volatile("s_waitcnt lgkmcnt(8)" ::: "memory")
#define WLG0  asm volatile("s_waitcnt lgkmcnt(0)" ::: "memory")
#define WVM2  asm volatile("s_waitcnt vmcnt(2)" ::: "memory")
#define WVM0  asm volatile("s_waitcnt vmcnt(0)" ::: "memory")
#define BARR  __builtin_amdgcn_s_barrier()
#define SCHEDB __builtin_amdgcn_sched_barrier(0)

#define LDA4(DST, BUF, ROFF)                                                    \
    _Pragma("unroll")                                                           \
    for (int mi = 0; mi < 4; ++mi) {                                            \
        DST[mi][0] = *(const short8*)&lsA[BUF][rA + (ROFF) + mi * 1024 + pc0];  \
        DST[mi][1] = *(const short8*)&lsA[BUF][rA + (ROFF) + mi * 1024 + pc1];  \
    }

#define LDB2(DST, BUF, ROFF)                                                    \
    _Pragma("unroll")                                                           \
    for (int ni = 0; ni < 2; ++ni) {                                            \
        DST[ni][0] = *(const short8*)&lsB[BUF][rB + (ROFF) + ni * 1024 + pc0];  \
        DST[ni][1] = *(const short8*)&lsB[BUF][rB + (ROFF) + ni * 1024 + pc1];  \
    }

#define RDA0(B) LDA4(a0, B, 0)
#define RDA1(B) LDA4(a1, B, 4096)
#define RDB0(B) LDB2(b0, B, 0)
#define RDB1(B) LDB2(b1, B, 2048)

#define MM16(AF, BF, MO, NO)                                                    \
    _Pragma("unroll")                                                           \
    for (int mi = 0; mi < 4; ++mi)                                              \
        _Pragma("unroll")                                                       \
        for (int ni = 0; ni < 2; ++ni)                                          \
            _Pragma("unroll")                                                   \
            for (int ks = 0; ks < 2; ++ks)                                      \
                acc[(MO) + mi][(NO) + ni] = __builtin_amdgcn_mfma_f32_16x16x32_bf16( \
                    AF[mi][ks], BF[ni][ks], acc[(MO) + mi][(NO) + ni], 0, 0, 0);

#define STAGE(LS, BUF, GP, KOFF, H)                                             \
    __builtin_amdgcn_global_load_lds(                                           \
        (const AS1 void*)((GP) + (size_t)((H) * 128) * K_DIM + (KOFF)),         \
        (AS3 void*)&LS[BUF][(H) * 128 * BK + dst], 16, 0, 0);                   \
    __builtin_amdgcn_global_load_lds(                                           \
        (const AS1 void*)((GP) + (size_t)((H) * 128 + 64) * K_DIM + (KOFF)),    \
        (AS3 void*)&LS[BUF][((H) * 128 + 64) * BK + dst], 16, 0, 0);

// standard phase: stage; barrier; counted-lgkm; MFMA; barrier
#define PH(STAGES, WAITM, MFMAS)                                                \
    STAGES                                                                      \
    BARR; WAITM; SCHEDB;                                                        \
    __builtin_amdgcn_s_setprio(1);                                              \
    MFMAS                                                                       \
    __builtin_amdgcn_s_setprio(0);                                              \
    BARR; SCHEDB;

// p3 phase: stage; vm-wait; barrier; read-ahead next tile's Q0; MFMA; barrier
#define PH3(STAGES, VMW, READS, MFMAS)                                          \
    STAGES                                                                      \
    VMW; BARR; SCHEDB;                                                          \
    READS                                                                       \
    WLG12; SCHEDB;                                                              \
    __builtin_amdgcn_s_setprio(1);                                              \
    MFMAS                                                                       \
    __builtin_amdgcn_s_setprio(0);                                              \
    BARR; SCHEDB;

#define TILE(c, n, k1, k2)                                                      \
    RDB1(c); RDA1(c);                                                           \
    PH(STAGE(lsA, n, gA, k1, 1), WLG12, MM16(a0, b0, 0, 0))                     \
    PH(STAGE(lsB, n, gB, k1, 0), WLG8,  MM16(a0, b1, 0, 2))                     \
    PH(STAGE(lsB, n, gB, k1, 1), WLG0,  MM16(a1, b0, 4, 0))                     \
    PH3(STAGE(lsA, c, gA, k2, 0), WVM2, RDA0(n); RDB0(n);, MM16(a1, b1, 4, 2))

__global__ __launch_bounds__(512, 2) void gemm_bt(const short* __restrict__ A,
                                                  const short* __restrict__ B,
                                                  float* __restrict__ C) {
    __shared__ __align__(16) short lsA[2][BMT * BK];   // 64 KiB
    __shared__ __align__(16) short lsB[2][BNT * BK];   // 64 KiB

    const int tid  = threadIdx.x;
    const int lane = tid & 63;
    const int wave = tid >> 6;
    const int wr   = wave >> 2;     // 0..1
    const int wc   = wave & 3;      // 0..3

    // bijective XCD map: 512 blocks, 64 per XCD; XCD x owns bn stripe
    // {2x, 2x+1} (4 MiB of B resident in its L2); consecutive j alternate bn.
    const int id  = blockIdx.x;
    const int xcd = id & 7;
    const int j   = id >> 3;
    const int bm  = j >> 1;                  // 0..31
    const int bn  = (xcd << 1) | (j & 1);    // 0..15

    // staging: thread covers row sr=tid>>3 (+64 per second load), phys chunk
    // tid&7; logical chunk = (tid&7)^(sr&7), invariant under row+64/+128.
    const int sr  = tid >> 3;
    const int csw = ((tid & 7) ^ (sr & 7)) << 3;
    const int dst = tid * 8;                 // = sr*64 + (tid&7)*8
    const short* gA = A + (size_t)(bm * BMT + sr) * K_DIM + csw;
    const short* gB = B + (size_t)(bn * BNT + sr) * K_DIM + csw;

    // fragment reads (chunk-XOR swizzle matches staging)
    const int frow = lane & 15;
    const int fc   = lane >> 4;
    const int fsw  = frow & 7;
    const int pc0  = (fc ^ fsw) << 3;        // ks=0 physical chunk * 8
    const int pc1  = ((4 + fc) ^ fsw) << 3;  // ks=1
    const int rA   = (wr * 128 + frow) * BK;
    const int rB   = (wc * 64 + frow) * BK;

    floatx4 acc[8][4];
#pragma unroll
    for (int mi = 0; mi < 8; ++mi)
#pragma unroll
        for (int ni = 0; ni < 4; ++ni)
            acc[mi][ni] = (floatx4){0.f, 0.f, 0.f, 0.f};

    short8 a0[4][2], a1[4][2], b0[2][2], b1[2][2];

    // prologue: A0,B0 -> buf0, A1h0 -> buf1; confirm A0,B0 (leave A1h0 in
    // flight); pre-read tile0's Q0 fragments.
    STAGE(lsA, 0, gA, 0, 0)
    STAGE(lsA, 0, gA, 0, 1)
    STAGE(lsB, 0, gB, 0, 0)
    STAGE(lsB, 0, gB, 0, 1)
    STAGE(lsA, 1, gA, 64, 0)
    WVM2; BARR; SCHEDB;
    RDA0(0); RDB0(0);

#pragma unroll 1
    for (int it = 0; it < 31; ++it) {
        TILE(0, 1, 64, 128)
        TILE(1, 0, 128, 192)
        gA += 128;
        gB += 128;
    }

    // tile 62 (buf0): stage only A63h1,B63; confirm all before reading buf1.
    RDB1(0); RDA1(0);
    PH(STAGE(lsA, 1, gA, 64, 1), WLG12, MM16(a0, b0, 0, 0))
    PH(STAGE(lsB, 1, gB, 64, 0), WLG8,  MM16(a0, b1, 0, 2))
    PH(STAGE(lsB, 1, gB, 64, 1), WLG0,  MM16(a1, b0, 4, 0))
    PH3(, WVM0, RDA0(1); RDB0(1);, MM16(a1, b1, 4, 2))

    // tile 63 (buf1): no stages.
    RDB1(1); RDA1(1);
    PH(, WLG12, MM16(a0, b0, 0, 0))
    PH(, WLG8,  MM16(a0, b1, 0, 2))
    PH(, WLG0,  MM16(a1, b0, 4, 0))
    SCHEDB;
    __builtin_amdgcn_s_setprio(1);
    MM16(a1, b1, 4, 2)
    __builtin_amdgcn_s_setprio(0);

    // Epilogue. C/D layout: col = lane&15, row = (lane>>4)*4 + reg.
    const int quad  = lane >> 4;
    const int crow0 = bm * BMT + wr * 128 + quad * 4;
    const int ccol0 = bn * BNT + wc * 64 + frow;
#pragma unroll
    for (int mi = 0; mi < 8; ++mi)
#pragma unroll
        for (int ni = 0; ni < 4; ++ni) {
            float* cp = C + (size_t)(crow0 + mi * 16) * O_DIM + (ccol0 + ni * 16);
#pragma unroll
            for (int r = 0; r < 4; ++r)
                cp[(size_t)r * O_DIM] = acc[mi][ni][r];
        }
}

extern "C" void kernel_launch(void* const* d_in, const int* in_sizes, int n_in,
                              void* d_out, int out_size, void* d_ws, size_t ws_size,
                              hipStream_t stream) {
    const float* x  = (const float*)d_in[0];
    const float* w  = (const float*)d_in[1];
    const float* ws = (const float*)d_in[2];
    float* out = (float*)d_out;

    short* xb = (short*)d_ws;                       // 64 MiB bf16 x
    short* wb = xb + (size_t)M_DIM * K_DIM;         // 32 MiB bf16 dequant w

    const size_t total_t = ((size_t)M_DIM * K_DIM + (size_t)O_DIM * K_DIM) / 8;
    cvt_fused<<<(unsigned)(total_t / 512), 512, 0, stream>>>(x, w, ws, xb, wb);

    gemm_bt<<<(M_DIM / BMT) * (O_DIM / BNT), 512, 0, stream>>>(xb, wb, out);
}